// Round 15
// baseline (280.539 us; speedup 1.0000x reference)
//
#include <hip/hip_runtime.h>
#include <hip/hip_bf16.h>
#include <stdint.h>

#define B_ 4
#define S_ 2048
#define D_ 1024
#define H_ 16
#define DK_ 64
#define GM (B_ * S_) /* 8192 */
#define GN D_        /* 1024 */
#define GK D_        /* 1024 */
#define BM 128
#define BN 128
#define BK 64
#define QBLK 128
#define KVBLK 64
#define NT (S_ / KVBLK) /* 32 kv tiles */
#define LDV 8192 /* VtM row stride (elements) */

typedef __attribute__((ext_vector_type(8))) __bf16 bf16x8;
typedef __attribute__((ext_vector_type(4))) float f32x4;
typedef __attribute__((ext_vector_type(4))) uint32_t u32x4;
typedef __attribute__((ext_vector_type(2))) uint32_t u32x2;

#if __has_builtin(__builtin_amdgcn_exp2f)
#define EXP2F(x) __builtin_amdgcn_exp2f(x)
#else
#define EXP2F(x) exp2f(x)
#endif

#define SCALE_LOG2E 0.18033688011112042f /* log2(e)/sqrt(DK) */

__device__ __forceinline__ uint16_t f2bf(float x) {
  uint32_t u = __builtin_bit_cast(uint32_t, x);
  u += 0x7fffu + ((u >> 16) & 1u); // RNE
  return (uint16_t)(u >> 16);
}
__device__ __forceinline__ uint32_t cvtpk(float lo, float hi) {
  uint32_t r;
  asm("v_cvt_pk_bf16_f32 %0, %1, %2" : "=v"(r) : "v"(lo), "v"(hi));
  return r;
}
__device__ __forceinline__ void gload_lds16(const void* g, void* l) {
  __builtin_amdgcn_global_load_lds(
      (const __attribute__((address_space(1))) void*)g,
      (__attribute__((address_space(3))) void*)l, 16, 0, 0);
}

// ---------------- f32 -> bf16 conversion pass (with per-buffer scale) --------
struct CvtArgs {
  const float* src[7];
  uint16_t* dst[7];
  int n[7];
  float scale[7];
};

__global__ __launch_bounds__(256) void cvt_f32_bf16(CvtArgs a) {
  const int z = blockIdx.z;
  const float* __restrict__ s = a.src[z];
  uint16_t* __restrict__ d = a.dst[z];
  const float sc = a.scale[z];
  const int nv = a.n[z] >> 3;
  const int stride = gridDim.x * blockDim.x;
  for (int i = blockIdx.x * blockDim.x + threadIdx.x; i < nv; i += stride) {
    f32x4 v0 = *(const f32x4*)(s + (size_t)i * 8);
    f32x4 v1 = *(const f32x4*)(s + (size_t)i * 8 + 4);
    union { uint16_t u[8]; u32x4 q; } o;
#pragma unroll
    for (int j = 0; j < 4; ++j) o.u[j] = f2bf(v0[j] * sc);
#pragma unroll
    for (int j = 0; j < 4; ++j) o.u[4 + j] = f2bf(v1[j] * sc);
    *(u32x4*)(d + (size_t)i * 8) = o.q;
  }
}

// ---------------- projection GEMM (all-bf16, global_load_lds staging) --------
// C[m,n] = sum_k A[m,k]*W[n,k] + bias[brow ? m : n]. Per-slot ldc/brow/swap.
struct Gemm3Args {
  const uint16_t* A[3];
  const uint16_t* W[3];
  const float* bias[3];
  float bscale[3];
  void* C[3];
  int ldc[3];
  int brow[3];
  int swap[3];
};

template <bool CF32>
__global__ __launch_bounds__(256, 2) void mha_gemm3(Gemm3Args args) {
  const int z = blockIdx.z;
  const char* __restrict__ A = (const char*)args.A[z];
  const char* __restrict__ W = (const char*)args.W[z];
  const float* __restrict__ bias = args.bias[z];
  const float bsc = args.bscale[z];
  void* __restrict__ C = args.C[z];
  const int ldc = args.ldc[z];
  const int brow = args.brow[z];

  __shared__ alignas(16) uint16_t tA[BM][BK];
  __shared__ alignas(16) uint16_t tW[BN][BK];

  const int tid = threadIdx.x;
  const int lane = tid & 63;
  const int wid = tid >> 6;
  const int wm = wid >> 1, wn = wid & 1;
  const int l16 = lane & 15, g = lane >> 4;

  const int m0 = (args.swap[z] ? blockIdx.x : blockIdx.y) * BM;
  const int n0 = (args.swap[z] ? blockIdx.y : blockIdx.x) * BN;

  f32x4 acc[4][4] = {};
  const int o = tid * 16;

  for (int k0 = 0; k0 < GK; k0 += BK) {
#pragma unroll
    for (int i = 0; i < 4; ++i) {
      const int oo = o + i * 4096;
      const int row = oo >> 7, colb = oo & 127;
      gload_lds16(A + (size_t)(m0 + row) * (GK * 2) + (size_t)k0 * 2 + colb,
                  ((char*)&tA[0][0]) + i * 4096 + wid * 1024);
      gload_lds16(W + (size_t)(n0 + row) * (GK * 2) + (size_t)k0 * 2 + colb,
                  ((char*)&tW[0][0]) + i * 4096 + wid * 1024);
    }
    __syncthreads();
#pragma unroll
    for (int kk = 0; kk < 2; ++kk) {
      const int kcol = kk * 32 + g * 8;
      bf16x8 af[4], bfr[4];
#pragma unroll
      for (int m = 0; m < 4; ++m)
        af[m] = *(const bf16x8*)&tA[wm * 64 + m * 16 + l16][kcol];
#pragma unroll
      for (int n = 0; n < 4; ++n)
        bfr[n] = *(const bf16x8*)&tW[wn * 64 + n * 16 + l16][kcol];
#pragma unroll
      for (int m = 0; m < 4; ++m)
#pragma unroll
        for (int n = 0; n < 4; ++n)
          acc[m][n] = __builtin_amdgcn_mfma_f32_16x16x32_bf16(
              af[m], bfr[n], acc[m][n], 0, 0, 0);
    }
    __syncthreads();
  }

#pragma unroll
  for (int n = 0; n < 4; ++n) {
    const int col = n0 + wn * 64 + n * 16 + l16;
    const float bvc = bias[col] * bsc; // used when !brow
#pragma unroll
    for (int m = 0; m < 4; ++m) {
      const int rbase = m0 + wm * 64 + m * 16 + g * 4;
#pragma unroll
      for (int r = 0; r < 4; ++r) {
        const float bv = brow ? bias[rbase + r] * bsc : bvc;
        const float v = acc[m][n][r] + bv;
        if (CF32)
          ((float*)C)[(size_t)(rbase + r) * ldc + col] = v;
        else
          ((uint16_t*)C)[(size_t)(rbase + r) * ldc + col] = f2bf(v);
      }
    }
  }
}

// ---------------- flash attention v8b ----------------------------------------
// Round-13 compute geometry + 3-buffer counted-vmcnt pipeline, race-fixed:
//  - prologue drains vmcnt(0) (no counting across the unordered 8-load group)
//  - sched_barrier(0) pins each tile's 4-load group so in-loop vmcnt(4)
//    counts a well-defined "4 newest" (HK pinning pattern).
__global__ __launch_bounds__(256) void mha_attn(
    const uint16_t* __restrict__ Q, const uint16_t* __restrict__ K,
    const uint16_t* __restrict__ Vt, uint16_t* __restrict__ O) {
  __shared__ alignas(16) char K_s[3][8192]; // [64 kv][128B]
  __shared__ alignas(16) char V_s[3][8192]; // [64 dk][128B kv]

  const int tid = threadIdx.x;
  const int lane = tid & 63;
  const int wid = tid >> 6;
  const int l16 = lane & 15, g = lane >> 4;

  // XCD-aware decode: d = xcd + 8*(h8*16 + qb); bh = xcd + 8*h8.
  const int d = blockIdx.x;
  const int bh = (d & 7) + ((d >> 7) << 3);
  const int qb = (d >> 3) & 15;
  const int b = bh >> 4, h = bh & 15;
  const int q0 = qb * QBLK;

  bf16x8 qf[2][2];
#pragma unroll
  for (int mi = 0; mi < 2; ++mi) {
    const uint16_t* qp = Q + ((size_t)(b * S_) + q0 + mi * 64 + wid * 16 + l16) * D_ +
                         h * DK_ + g * 8;
    qf[mi][0] = *(const bf16x8*)qp;
    qf[mi][1] = *(const bf16x8*)(qp + 32);
  }

  f32x4 o_acc[2][4] = {}; // o^T[dk=n*16+g*4+r][q=l16]
  float lpart[2] = {0.f, 0.f};

  const char* Kb = (const char*)K;
  const char* Vtb = (const char*)Vt;

  int srow[2], scol[2];
#pragma unroll
  for (int i = 0; i < 2; ++i) {
    const int oo = tid * 16 + i * 4096;
    srow[i] = oo >> 7;                            // kv row (K) / dk row (V)
    scol[i] = (oo & 127) ^ ((srow[i] & 7) << 4);  // pre-swizzled src col
  }

#define ISSUE_LOADS(buf, kv0)                                                  \
  {                                                                            \
    _Pragma("unroll") for (int i = 0; i < 2; ++i) {                            \
      gload_lds16(Kb + (((size_t)b * S_ + (kv0) + srow[i]) * D_ + h * DK_) * 2 \
                      + scol[i],                                               \
                  &K_s[buf][0] + i * 4096 + wid * 1024);                       \
      gload_lds16(Vtb + (((size_t)h * DK_ + srow[i]) * LDV + b * S_ + (kv0))   \
                          * 2 + scol[i],                                       \
                  &V_s[buf][0] + i * 4096 + wid * 1024);                       \
    }                                                                          \
  }

  // Prologue: issue tiles 0 and 1, then FULL drain (no counting hazard here).
  ISSUE_LOADS(0, 0);
  ISSUE_LOADS(1, KVBLK);
  asm volatile("s_waitcnt vmcnt(0)" ::: "memory");
  __builtin_amdgcn_s_barrier();
  __builtin_amdgcn_sched_barrier(0);

  const int bsrc = l16 + ((g & 1) << 5); // shuffle source base lane
  const int gsel = g >> 1;

  int cur = 0;
  for (int t = 0; t < NT; ++t) {
    if (t + 2 < NT) {
      ISSUE_LOADS((t + 2) % 3, (t + 2) * KVBLK);
    }
    // Pin this tile's 4-load group: nothing crosses; keeps vmcnt counting
    // well-defined (each group issues contiguously, groups in order).
    __builtin_amdgcn_sched_barrier(0);

    // ---- swapped QK^T: sacc[mi][n] = S^T[kv=n*16+g*4+r][q=l16] ----
    f32x4 sacc[2][4] = {};
#pragma unroll
    for (int ks = 0; ks < 2; ++ks) {
      const int kcolb = ks * 64 + g * 16;
#pragma unroll
      for (int n = 0; n < 4; ++n) {
        const int kvr = n * 16 + l16;
        const bf16x8 kf =
            *(const bf16x8*)(&K_s[cur][0] + kvr * 128 + (kcolb ^ ((kvr & 7) << 4)));
#pragma unroll
        for (int mi = 0; mi < 2; ++mi)
          sacc[mi][n] = __builtin_amdgcn_mfma_f32_16x16x32_bf16(
              kf, qf[mi][ks], sacc[mi][n], 0, 0, 0);
      }
    }

    // ---- exp2 + pack + cross-g redistribution (P stays in regs) ----
    uint32_t pb[2][2][4];
#pragma unroll
    for (int mi = 0; mi < 2; ++mi) {
      uint32_t pk0[4][2];
#pragma unroll
      for (int n = 0; n < 4; ++n) {
        float e0 = EXP2F(sacc[mi][n][0]);
        float e1 = EXP2F(sacc[mi][n][1]);
        float e2 = EXP2F(sacc[mi][n][2]);
        float e3 = EXP2F(sacc[mi][n][3]);
        lpart[mi] += (e0 + e1) + (e2 + e3);
        pk0[n][0] = cvtpk(e0, e1);
        pk0[n][1] = cvtpk(e2, e3);
      }
#pragma unroll
      for (int ks = 0; ks < 2; ++ks)
#pragma unroll
        for (int jp = 0; jp < 4; ++jp) {
          const int srcl = bsrc + ((jp >> 1) << 4);
          const uint32_t va = __shfl(pk0[2 * ks][jp & 1], srcl, 64);
          const uint32_t vb = __shfl(pk0[2 * ks + 1][jp & 1], srcl, 64);
          pb[mi][ks][jp] = gsel ? vb : va;
        }
    }

    // ---- PV: o^T = mfma(V^T, P^T) ----
#pragma unroll
    for (int ks = 0; ks < 2; ++ks) {
      const int kcolb = ks * 64 + g * 16;
      bf16x8 pf[2];
#pragma unroll
      for (int mi = 0; mi < 2; ++mi) {
        u32x4 t_ = {pb[mi][ks][0], pb[mi][ks][1], pb[mi][ks][2], pb[mi][ks][3]};
        pf[mi] = __builtin_bit_cast(bf16x8, t_);
      }
#pragma unroll
      for (int n = 0; n < 4; ++n) {
        const int dkr = n * 16 + l16;
        const bf16x8 vf =
            *(const bf16x8*)(&V_s[cur][0] + dkr * 128 + (kcolb ^ ((dkr & 7) << 4)));
#pragma unroll
        for (int mi = 0; mi < 2; ++mi)
          o_acc[mi][n] = __builtin_amdgcn_mfma_f32_16x16x32_bf16(
              vf, pf[mi], o_acc[mi][n], 0, 0, 0);
      }
    }

    // ---- counted-vmcnt barrier (t+2 prefetch stays in flight) ----
    if (t < NT - 1) {
      if (t + 2 < NT)
        asm volatile("s_waitcnt vmcnt(4)" ::: "memory");
      else
        asm volatile("s_waitcnt vmcnt(0)" ::: "memory");
      __builtin_amdgcn_s_barrier();
      __builtin_amdgcn_sched_barrier(0);
    }
    cur = (cur == 2) ? 0 : cur + 1;
  }

  // ---- l-reduce across the 4 g-groups; normalize; packed 8B stores ----
  float linv[2];
#pragma unroll
  for (int mi = 0; mi < 2; ++mi) {
    float s_ = lpart[mi];
    s_ += __shfl_xor(s_, 16, 64);
    s_ += __shfl_xor(s_, 32, 64);
    linv[mi] = 1.f / s_;
  }
#pragma unroll
  for (int mi = 0; mi < 2; ++mi) {
    const size_t row = (size_t)b * S_ + q0 + mi * 64 + wid * 16 + l16;
    uint16_t* op = O + row * D_ + h * DK_ + g * 4;
#pragma unroll
    for (int n = 0; n < 4; ++n) {
      u32x2 w;
      w[0] = cvtpk(o_acc[mi][n][0] * linv[mi], o_acc[mi][n][1] * linv[mi]);
      w[1] = cvtpk(o_acc[mi][n][2] * linv[mi], o_acc[mi][n][3] * linv[mi]);
      *(u32x2*)(op + n * 16) = w;
    }
  }
}

extern "C" void kernel_launch(void* const* d_in, const int* in_sizes, int n_in,
                              void* d_out, int out_size, void* d_ws,
                              size_t ws_size, hipStream_t stream) {
  (void)in_sizes; (void)n_in; (void)out_size; (void)ws_size;

  const float* query = (const float*)d_in[0];
  const float* key_ = (const float*)d_in[1];
  const float* value = (const float*)d_in[2];
  const float* Wq = (const float*)d_in[3];
  const float* bq = (const float*)d_in[4];
  const float* Wk = (const float*)d_in[5];
  const float* bk = (const float*)d_in[6];
  const float* Wv = (const float*)d_in[7];
  const float* bv = (const float*)d_in[8];
  const float* Wo = (const float*)d_in[9];
  const float* bo = (const float*)d_in[10];

  const size_t nact = (size_t)GM * GN;
  const size_t nw = (size_t)GN * GK;
  uint16_t* p = (uint16_t*)d_ws;
  uint16_t* qb = p; p += nact;
  uint16_t* kb = p; p += nact;
  uint16_t* vb = p; p += nact;
  uint16_t* wq = p; p += nw;
  uint16_t* wk = p; p += nw;
  uint16_t* wv = p; p += nw;
  uint16_t* wo = p; p += nw;
  uint16_t* Qp = p; p += nact;
  uint16_t* Kp = p; p += nact;
  uint16_t* Vt = p; p += nact; // VtM[1024][8192]
  uint16_t* Cp = p; p += nact;

  // ---- 1) convert to bf16 (Wq pre-scaled by log2(e)/sqrt(dk)) ----
  CvtArgs ca;
  const float* srcs[7] = {query, key_, value, Wq, Wk, Wv, Wo};
  uint16_t* dsts[7] = {qb, kb, vb, wq, wk, wv, wo};
  const int cnts[7] = {(int)nact, (int)nact, (int)nact, (int)nw,
                       (int)nw,   (int)nw,   (int)nw};
  for (int i = 0; i < 7; ++i) {
    ca.src[i] = srcs[i]; ca.dst[i] = dsts[i]; ca.n[i] = cnts[i];
    ca.scale[i] = 1.0f;
  }
  ca.scale[3] = SCALE_LOG2E; // Wq
  cvt_f32_bf16<<<dim3(512, 1, 7), dim3(256), 0, stream>>>(ca);

  // ---- 2) Q, K, VtM projections in ONE launch (z=2 uses swapped coords) ----
  Gemm3Args g1;
  g1.A[0] = qb; g1.A[1] = kb; g1.A[2] = wv;
  g1.W[0] = wq; g1.W[1] = wk; g1.W[2] = vb;
  g1.bias[0] = bq; g1.bias[1] = bk; g1.bias[2] = bv;
  g1.bscale[0] = SCALE_LOG2E; g1.bscale[1] = 1.0f; g1.bscale[2] = 1.0f;
  g1.C[0] = Qp; g1.C[1] = Kp; g1.C[2] = Vt;
  g1.ldc[0] = GN; g1.ldc[1] = GN; g1.ldc[2] = LDV;
  g1.brow[0] = 0; g1.brow[1] = 0; g1.brow[2] = 1;
  g1.swap[0] = 0; g1.swap[1] = 0; g1.swap[2] = 1;
  mha_gemm3<false>
      <<<dim3(GN / BN, GM / BM, 3), dim3(256), 0, stream>>>(g1);

  // ---- 3) attention ----
  mha_attn<<<dim3((S_ / QBLK) * B_ * H_), dim3(256), 0, stream>>>(Qp, Kp, Vt, Cp);

  // ---- 4) output projection (f32 out to d_out) ----
  Gemm3Args g2;
  g2.A[0] = Cp; g2.W[0] = wo; g2.bias[0] = bo; g2.C[0] = d_out;
  g2.bscale[0] = 1.0f; g2.ldc[0] = GN; g2.brow[0] = 0; g2.swap[0] = 0;
  g2.A[1] = g2.A[0]; g2.W[1] = g2.W[0]; g2.bias[1] = g2.bias[0];
  g2.C[1] = g2.C[0]; g2.bscale[1] = 1.0f; g2.ldc[1] = GN;
  g2.brow[1] = 0; g2.swap[1] = 0;
  g2.A[2] = g2.A[0]; g2.W[2] = g2.W[0]; g2.bias[2] = g2.bias[0];
  g2.C[2] = g2.C[0]; g2.bscale[2] = 1.0f; g2.ldc[2] = GN;
  g2.brow[2] = 0; g2.swap[2] = 0;
  mha_gemm3<true>
      <<<dim3(GN / BN, GM / BM, 1), dim3(256), 0, stream>>>(g2);
}

// Round 17
// 263.613 us; speedup vs baseline: 1.0642x; 1.0642x over previous
//
#include <hip/hip_runtime.h>
#include <hip/hip_bf16.h>
#include <stdint.h>

#define B_ 4
#define S_ 2048
#define D_ 1024
#define H_ 16
#define DK_ 64
#define GM (B_ * S_) /* 8192 */
#define GN D_        /* 1024 */
#define GK D_        /* 1024 */
#define BM 128
#define BN 128
#define BK 64
#define QBLK 128
#define KVBLK 64

typedef __attribute__((ext_vector_type(8))) __bf16 bf16x8;
typedef __attribute__((ext_vector_type(4))) float f32x4;
typedef __attribute__((ext_vector_type(4))) uint32_t u32x4;
typedef __attribute__((ext_vector_type(2))) uint32_t u32x2;

#if __has_builtin(__builtin_amdgcn_exp2f)
#define EXP2F(x) __builtin_amdgcn_exp2f(x)
#else
#define EXP2F(x) exp2f(x)
#endif

#define SCALE_LOG2E 0.18033688011112042f /* log2(e)/sqrt(DK) */

__device__ __forceinline__ uint16_t f2bf(float x) {
  uint32_t u = __builtin_bit_cast(uint32_t, x);
  u += 0x7fffu + ((u >> 16) & 1u); // RNE
  return (uint16_t)(u >> 16);
}
__device__ __forceinline__ uint32_t cvtpk(float lo, float hi) {
  uint32_t r;
  asm("v_cvt_pk_bf16_f32 %0, %1, %2" : "=v"(r) : "v"(lo), "v"(hi));
  return r;
}
__device__ __forceinline__ void gload_lds16(const void* g, void* l) {
  __builtin_amdgcn_global_load_lds(
      (const __attribute__((address_space(1))) void*)g,
      (__attribute__((address_space(3))) void*)l, 16, 0, 0);
}

// ---------------- f32 -> bf16 conversion pass (with per-buffer scale) --------
struct CvtArgs {
  const float* src[7];
  uint16_t* dst[7];
  int n[7];
  float scale[7];
};

__global__ __launch_bounds__(256) void cvt_f32_bf16(CvtArgs a) {
  const int z = blockIdx.z;
  const float* __restrict__ s = a.src[z];
  uint16_t* __restrict__ d = a.dst[z];
  const float sc = a.scale[z];
  const int nv = a.n[z] >> 3;
  const int stride = gridDim.x * blockDim.x;
  for (int i = blockIdx.x * blockDim.x + threadIdx.x; i < nv; i += stride) {
    f32x4 v0 = *(const f32x4*)(s + (size_t)i * 8);
    f32x4 v1 = *(const f32x4*)(s + (size_t)i * 8 + 4);
    union { uint16_t u[8]; u32x4 q; } o;
#pragma unroll
    for (int j = 0; j < 4; ++j) o.u[j] = f2bf(v0[j] * sc);
#pragma unroll
    for (int j = 0; j < 4; ++j) o.u[4 + j] = f2bf(v1[j] * sc);
    *(u32x4*)(d + (size_t)i * 8) = o.q;
  }
}

// ---------------- projection GEMM (all-bf16, global_load_lds staging) --------
// Round-10 verbatim (best-measured projection phase).
struct Gemm3Args {
  const uint16_t* A[3];
  const uint16_t* W[3];
  const float* bias[3];
  float bscale[3];
  void* C[3];
};

template <bool CF32>
__global__ __launch_bounds__(256, 2) void mha_gemm3(Gemm3Args args) {
  const int z = blockIdx.z;
  const char* __restrict__ A = (const char*)args.A[z];
  const char* __restrict__ W = (const char*)args.W[z];
  const float* __restrict__ bias = args.bias[z];
  const float bsc = args.bscale[z];
  void* __restrict__ C = args.C[z];

  __shared__ alignas(16) uint16_t tA[BM][BK];
  __shared__ alignas(16) uint16_t tW[BN][BK];

  const int tid = threadIdx.x;
  const int lane = tid & 63;
  const int wid = tid >> 6;
  const int wm = wid >> 1, wn = wid & 1;
  const int l16 = lane & 15, g = lane >> 4;

  const int m0 = blockIdx.y * BM;
  const int n0 = blockIdx.x * BN;

  f32x4 acc[4][4] = {};
  const int o = tid * 16;

  for (int k0 = 0; k0 < GK; k0 += BK) {
#pragma unroll
    for (int i = 0; i < 4; ++i) {
      const int oo = o + i * 4096;
      const int row = oo >> 7, colb = oo & 127;
      gload_lds16(A + (size_t)(m0 + row) * (GK * 2) + (size_t)k0 * 2 + colb,
                  ((char*)&tA[0][0]) + i * 4096 + wid * 1024);
      gload_lds16(W + (size_t)(n0 + row) * (GK * 2) + (size_t)k0 * 2 + colb,
                  ((char*)&tW[0][0]) + i * 4096 + wid * 1024);
    }
    __syncthreads();
#pragma unroll
    for (int kk = 0; kk < 2; ++kk) {
      const int kcol = kk * 32 + g * 8;
      bf16x8 af[4], bfr[4];
#pragma unroll
      for (int m = 0; m < 4; ++m)
        af[m] = *(const bf16x8*)&tA[wm * 64 + m * 16 + l16][kcol];
#pragma unroll
      for (int n = 0; n < 4; ++n)
        bfr[n] = *(const bf16x8*)&tW[wn * 64 + n * 16 + l16][kcol];
#pragma unroll
      for (int m = 0; m < 4; ++m)
#pragma unroll
        for (int n = 0; n < 4; ++n)
          acc[m][n] = __builtin_amdgcn_mfma_f32_16x16x32_bf16(
              af[m], bfr[n], acc[m][n], 0, 0, 0);
    }
    __syncthreads();
  }

#pragma unroll
  for (int n = 0; n < 4; ++n) {
    const int col = n0 + wn * 64 + n * 16 + l16;
    const float bv = bias[col] * bsc;
#pragma unroll
    for (int m = 0; m < 4; ++m) {
      const int rbase = m0 + wm * 64 + m * 16 + g * 4;
#pragma unroll
      for (int r = 0; r < 4; ++r) {
        const float v = acc[m][n][r] + bv;
        if (CF32)
          ((float*)C)[(size_t)(rbase + r) * GN + col] = v;
        else
          ((uint16_t*)C)[(size_t)(rbase + r) * GN + col] = f2bf(v);
      }
    }
  }
}

// ---------------- V transpose: Vp[b*S+s][h*64+dk] -> Vt[(b*16+h)*64+dk][s] ---
// Round-10 verbatim.
__global__ __launch_bounds__(256) void transpose_v(
    const uint16_t* __restrict__ Vp, uint16_t* __restrict__ Vt) {
  __shared__ alignas(16) char T[64 * 128];
  const int tid = threadIdx.x;
  const int s0 = blockIdx.x * 64;
  const int h = blockIdx.y;
  const int bb = blockIdx.z;
#pragma unroll
  for (int it = 0; it < 2; ++it) {
    const int idx = tid + it * 256;
    const int row = idx >> 3;         // s within tile
    const int colb = (idx & 7) * 16;  // dk byte col
    const u32x4 v = *(const u32x4*)((const char*)Vp +
        (((size_t)bb * S_ + s0 + row) * D_ + h * DK_) * 2 + colb);
    *(u32x4*)(T + row * 128 + (colb ^ (((row >> 3) & 7) << 4))) = v;
  }
  __syncthreads();
#pragma unroll
  for (int it = 0; it < 2; ++it) {
    const int idx = tid + it * 256;
    const int dk = idx >> 3;
    const int sc = (idx & 7) * 8;
    union { uint16_t u[8]; u32x4 q; } o;
#pragma unroll
    for (int j = 0; j < 8; ++j) {
      const int row = sc + j;
      o.u[j] =
          *(const uint16_t*)(T + row * 128 + ((dk * 2) ^ (((row >> 3) & 7) << 4)));
    }
    *(u32x4*)((char*)Vt +
              (((size_t)(bb * H_ + h) * DK_ + dk) * S_ + s0 + sc) * 2) = o.q;
  }
}

// ---------------- flash attention (round-13 attn; Vt layout = round-10) ------
// 4 waves, QBLK=128, KVBLK=64 (32 KB LDS). Swapped QK^T, reg-P via cvt_pk +
// shfl, dbuf + 1 barrier/tile, XCD-aware decode. V staged from
// Vt[(b*16+h)*64+dk][s] (transpose_v output, row stride S_).
__global__ __launch_bounds__(256) void mha_attn(
    const uint16_t* __restrict__ Q, const uint16_t* __restrict__ K,
    const uint16_t* __restrict__ Vt, uint16_t* __restrict__ O) {
  __shared__ alignas(16) char K_s[2][8192]; // [64 kv][128B]
  __shared__ alignas(16) char V_s[2][8192]; // [64 dk][128B kv]

  const int tid = threadIdx.x;
  const int lane = tid & 63;
  const int wid = tid >> 6;
  const int l16 = lane & 15, g = lane >> 4;

  // XCD-aware decode: d = xcd + 8*(h8*16 + qb); bh = xcd + 8*h8.
  const int d = blockIdx.x;
  const int bh = (d & 7) + ((d >> 7) << 3);
  const int qb = (d >> 3) & 15;
  const int b = bh >> 4, h = bh & 15;
  const int q0 = qb * QBLK;

  bf16x8 qf[2][2];
#pragma unroll
  for (int mi = 0; mi < 2; ++mi) {
    const uint16_t* qp = Q + ((size_t)(b * S_) + q0 + mi * 64 + wid * 16 + l16) * D_ +
                         h * DK_ + g * 8;
    qf[mi][0] = *(const bf16x8*)qp;
    qf[mi][1] = *(const bf16x8*)(qp + 32);
  }

  f32x4 o_acc[2][4] = {}; // o^T[dk=n*16+g*4+r][q=l16]
  float lpart[2] = {0.f, 0.f};

  const char* Kb = (const char*)K;
  const char* Vtb = (const char*)Vt;

  int srow[2], scol[2];
#pragma unroll
  for (int i = 0; i < 2; ++i) {
    const int oo = tid * 16 + i * 4096;
    srow[i] = oo >> 7;                            // kv row (K) / dk row (V)
    scol[i] = (oo & 127) ^ ((srow[i] & 7) << 4);  // pre-swizzled src col
  }

#define ISSUE_LOADS(buf, kv0)                                                  \
  {                                                                            \
    _Pragma("unroll") for (int i = 0; i < 2; ++i) {                            \
      gload_lds16(Kb + (((size_t)b * S_ + (kv0) + srow[i]) * D_ + h * DK_) * 2 \
                      + scol[i],                                               \
                  &K_s[buf][0] + i * 4096 + wid * 1024);                       \
      gload_lds16(Vtb + (((size_t)bh * DK_ + srow[i]) * S_ + (kv0)) * 2        \
                      + scol[i],                                               \
                  &V_s[buf][0] + i * 4096 + wid * 1024);                       \
    }                                                                          \
  }

  ISSUE_LOADS(0, 0);
  __syncthreads();
  int cur = 0;

  const int bsrc = l16 + ((g & 1) << 5); // shuffle source base lane
  const int gsel = g >> 1;

  for (int kv0 = 0; kv0 < S_; kv0 += KVBLK) {
    const bool last = (kv0 + KVBLK >= S_);
    if (!last) ISSUE_LOADS(cur ^ 1, kv0 + KVBLK);

    // ---- swapped QK^T: sacc[mi][n] = S^T[kv=n*16+g*4+r][q=l16] ----
    f32x4 sacc[2][4] = {};
#pragma unroll
    for (int ks = 0; ks < 2; ++ks) {
      const int kcolb = ks * 64 + g * 16;
#pragma unroll
      for (int n = 0; n < 4; ++n) {
        const int kvr = n * 16 + l16;
        const bf16x8 kf =
            *(const bf16x8*)(&K_s[cur][0] + kvr * 128 + (kcolb ^ ((kvr & 7) << 4)));
#pragma unroll
        for (int mi = 0; mi < 2; ++mi)
          sacc[mi][n] = __builtin_amdgcn_mfma_f32_16x16x32_bf16(
              kf, qf[mi][ks], sacc[mi][n], 0, 0, 0);
      }
    }

    // ---- exp2 + pack + cross-g redistribution (P stays in regs) ----
    uint32_t pb[2][2][4];
#pragma unroll
    for (int mi = 0; mi < 2; ++mi) {
      uint32_t pk0[4][2];
#pragma unroll
      for (int n = 0; n < 4; ++n) {
        float e0 = EXP2F(sacc[mi][n][0]);
        float e1 = EXP2F(sacc[mi][n][1]);
        float e2 = EXP2F(sacc[mi][n][2]);
        float e3 = EXP2F(sacc[mi][n][3]);
        lpart[mi] += (e0 + e1) + (e2 + e3);
        pk0[n][0] = cvtpk(e0, e1);
        pk0[n][1] = cvtpk(e2, e3);
      }
#pragma unroll
      for (int ks = 0; ks < 2; ++ks)
#pragma unroll
        for (int jp = 0; jp < 4; ++jp) {
          const int srcl = bsrc + ((jp >> 1) << 4);
          const uint32_t va = __shfl(pk0[2 * ks][jp & 1], srcl, 64);
          const uint32_t vb = __shfl(pk0[2 * ks + 1][jp & 1], srcl, 64);
          pb[mi][ks][jp] = gsel ? vb : va;
        }
    }

    // ---- PV: o^T = mfma(V^T, P^T) ----
#pragma unroll
    for (int ks = 0; ks < 2; ++ks) {
      const int kcolb = ks * 64 + g * 16;
      bf16x8 pf[2];
#pragma unroll
      for (int mi = 0; mi < 2; ++mi) {
        u32x4 t = {pb[mi][ks][0], pb[mi][ks][1], pb[mi][ks][2], pb[mi][ks][3]};
        pf[mi] = __builtin_bit_cast(bf16x8, t);
      }
#pragma unroll
      for (int n = 0; n < 4; ++n) {
        const int dkr = n * 16 + l16;
        const bf16x8 vf =
            *(const bf16x8*)(&V_s[cur][0] + dkr * 128 + (kcolb ^ ((dkr & 7) << 4)));
#pragma unroll
        for (int mi = 0; mi < 2; ++mi)
          o_acc[mi][n] = __builtin_amdgcn_mfma_f32_16x16x32_bf16(
              vf, pf[mi], o_acc[mi][n], 0, 0, 0);
      }
    }

    if (!last) __syncthreads();
    cur ^= 1;
  }

  // ---- l-reduce across the 4 g-groups; normalize; packed 8B stores ----
  float linv[2];
#pragma unroll
  for (int mi = 0; mi < 2; ++mi) {
    float s_ = lpart[mi];
    s_ += __shfl_xor(s_, 16, 64);
    s_ += __shfl_xor(s_, 32, 64);
    linv[mi] = 1.f / s_;
  }
#pragma unroll
  for (int mi = 0; mi < 2; ++mi) {
    const size_t row = (size_t)b * S_ + q0 + mi * 64 + wid * 16 + l16;
    uint16_t* op = O + row * D_ + h * DK_ + g * 4;
#pragma unroll
    for (int n = 0; n < 4; ++n) {
      u32x2 w;
      w[0] = cvtpk(o_acc[mi][n][0] * linv[mi], o_acc[mi][n][1] * linv[mi]);
      w[1] = cvtpk(o_acc[mi][n][2] * linv[mi], o_acc[mi][n][3] * linv[mi]);
      *(u32x2*)(op + n * 16) = w;
    }
  }
}

extern "C" void kernel_launch(void* const* d_in, const int* in_sizes, int n_in,
                              void* d_out, int out_size, void* d_ws,
                              size_t ws_size, hipStream_t stream) {
  (void)in_sizes; (void)n_in; (void)out_size; (void)ws_size;

  const float* query = (const float*)d_in[0];
  const float* key_ = (const float*)d_in[1];
  const float* value = (const float*)d_in[2];
  const float* Wq = (const float*)d_in[3];
  const float* bq = (const float*)d_in[4];
  const float* Wk = (const float*)d_in[5];
  const float* bk = (const float*)d_in[6];
  const float* Wv = (const float*)d_in[7];
  const float* bv = (const float*)d_in[8];
  const float* Wo = (const float*)d_in[9];
  const float* bo = (const float*)d_in[10];

  const size_t nact = (size_t)GM * GN;
  const size_t nw = (size_t)GN * GK;
  uint16_t* p = (uint16_t*)d_ws;
  uint16_t* qb = p; p += nact;
  uint16_t* kb = p; p += nact;
  uint16_t* vb = p; p += nact;
  uint16_t* wq = p; p += nw;
  uint16_t* wk = p; p += nw;
  uint16_t* wv = p; p += nw;
  uint16_t* wo = p; p += nw;
  uint16_t* Qp = p; p += nact;
  uint16_t* Kp = p; p += nact;
  uint16_t* Vp = p; p += nact;
  uint16_t* Cp = p; p += nact;
  uint16_t* Vt = qb; // reuse: qb dead after QKV GEMM

  // ---- 1) convert to bf16 (Wq pre-scaled by log2(e)/sqrt(dk)) ----
  CvtArgs ca;
  const float* srcs[7] = {query, key_, value, Wq, Wk, Wv, Wo};
  uint16_t* dsts[7] = {qb, kb, vb, wq, wk, wv, wo};
  const int cnts[7] = {(int)nact, (int)nact, (int)nact, (int)nw,
                       (int)nw,   (int)nw,   (int)nw};
  for (int i = 0; i < 7; ++i) {
    ca.src[i] = srcs[i]; ca.dst[i] = dsts[i]; ca.n[i] = cnts[i];
    ca.scale[i] = 1.0f;
  }
  ca.scale[3] = SCALE_LOG2E; // Wq
  cvt_f32_bf16<<<dim3(512, 1, 7), dim3(256), 0, stream>>>(ca);

  // ---- 2) QKV projections (Q branch bias also pre-scaled) ----
  Gemm3Args g1;
  g1.A[0] = qb; g1.A[1] = kb; g1.A[2] = vb;
  g1.W[0] = wq; g1.W[1] = wk; g1.W[2] = wv;
  g1.bias[0] = bq; g1.bias[1] = bk; g1.bias[2] = bv;
  g1.bscale[0] = SCALE_LOG2E; g1.bscale[1] = 1.0f; g1.bscale[2] = 1.0f;
  g1.C[0] = Qp; g1.C[1] = Kp; g1.C[2] = Vp;
  mha_gemm3<false>
      <<<dim3(GN / BN, GM / BM, 3), dim3(256), 0, stream>>>(g1);

  // ---- 3) V transpose (into dead qb buffer) ----
  transpose_v<<<dim3(S_ / 64, H_, B_), dim3(256), 0, stream>>>(Vp, Vt);

  // ---- 4) attention (1D grid, XCD-swizzled decode in-kernel) ----
  mha_attn<<<dim3((S_ / QBLK) * B_ * H_), dim3(256), 0, stream>>>(Qp, Kp, Vt, Cp);

  // ---- 5) output projection (f32 out to d_out) ----
  Gemm3Args g2;
  g2.A[0] = Cp; g2.W[0] = wo; g2.bias[0] = bo; g2.C[0] = d_out;
  g2.bscale[0] = 1.0f;
  g2.A[1] = g2.A[0]; g2.W[1] = g2.W[0]; g2.bias[1] = g2.bias[0]; g2.C[1] = g2.C[0];
  g2.bscale[1] = 1.0f;
  g2.A[2] = g2.A[0]; g2.W[2] = g2.W[0]; g2.bias[2] = g2.bias[0]; g2.C[2] = g2.C[0];
  g2.bscale[2] = 1.0f;
  mha_gemm3<true>
      <<<dim3(GN / BN, GM / BM, 1), dim3(256), 0, stream>>>(g2);
}

// Round 18
// 252.600 us; speedup vs baseline: 1.1106x; 1.0436x over previous
//
#include <hip/hip_runtime.h>
#include <hip/hip_bf16.h>
#include <stdint.h>

#define B_ 4
#define S_ 2048
#define D_ 1024
#define H_ 16
#define DK_ 64
#define GM (B_ * S_) /* 8192 */
#define GN D_        /* 1024 */
#define GK D_        /* 1024 */
#define BM 128
#define BN 128
#define BK 64
#define QBLK 128
#define KVBLK 128

typedef __attribute__((ext_vector_type(8))) __bf16 bf16x8;
typedef __attribute__((ext_vector_type(4))) float f32x4;
typedef __attribute__((ext_vector_type(4))) uint32_t u32x4;
typedef __attribute__((ext_vector_type(2))) uint32_t u32x2;

#if __has_builtin(__builtin_amdgcn_exp2f)
#define EXP2F(x) __builtin_amdgcn_exp2f(x)
#else
#define EXP2F(x) exp2f(x)
#endif

#define SCALE_LOG2E 0.18033688011112042f /* log2(e)/sqrt(DK) */

__device__ __forceinline__ uint16_t f2bf(float x) {
  uint32_t u = __builtin_bit_cast(uint32_t, x);
  u += 0x7fffu + ((u >> 16) & 1u); // RNE
  return (uint16_t)(u >> 16);
}
__device__ __forceinline__ uint32_t cvtpk(float lo, float hi) {
  uint32_t r;
  asm("v_cvt_pk_bf16_f32 %0, %1, %2" : "=v"(r) : "v"(lo), "v"(hi));
  return r;
}
__device__ __forceinline__ void gload_lds16(const void* g, void* l) {
  __builtin_amdgcn_global_load_lds(
      (const __attribute__((address_space(1))) void*)g,
      (__attribute__((address_space(3))) void*)l, 16, 0, 0);
}

// ---------------- f32 -> bf16 conversion pass (with per-buffer scale) --------
struct CvtArgs {
  const float* src[7];
  uint16_t* dst[7];
  int n[7];
  float scale[7];
};

__global__ __launch_bounds__(256) void cvt_f32_bf16(CvtArgs a) {
  const int z = blockIdx.z;
  const float* __restrict__ s = a.src[z];
  uint16_t* __restrict__ d = a.dst[z];
  const float sc = a.scale[z];
  const int nv = a.n[z] >> 3;
  const int stride = gridDim.x * blockDim.x;
  for (int i = blockIdx.x * blockDim.x + threadIdx.x; i < nv; i += stride) {
    f32x4 v0 = *(const f32x4*)(s + (size_t)i * 8);
    f32x4 v1 = *(const f32x4*)(s + (size_t)i * 8 + 4);
    union { uint16_t u[8]; u32x4 q; } o;
#pragma unroll
    for (int j = 0; j < 4; ++j) o.u[j] = f2bf(v0[j] * sc);
#pragma unroll
    for (int j = 0; j < 4; ++j) o.u[4 + j] = f2bf(v1[j] * sc);
    *(u32x4*)(d + (size_t)i * 8) = o.q;
  }
}

// ---------------- projection GEMM (all-bf16, global_load_lds staging) --------
struct Gemm3Args {
  const uint16_t* A[3];
  const uint16_t* W[3];
  const float* bias[3];
  float bscale[3];
  void* C[3];
};

template <bool CF32>
__global__ __launch_bounds__(256, 2) void mha_gemm3(Gemm3Args args) {
  const int z = blockIdx.z;
  const char* __restrict__ A = (const char*)args.A[z];
  const char* __restrict__ W = (const char*)args.W[z];
  const float* __restrict__ bias = args.bias[z];
  const float bsc = args.bscale[z];
  void* __restrict__ C = args.C[z];

  __shared__ alignas(16) uint16_t tA[BM][BK];
  __shared__ alignas(16) uint16_t tW[BN][BK];

  const int tid = threadIdx.x;
  const int lane = tid & 63;
  const int wid = tid >> 6;
  const int wm = wid >> 1, wn = wid & 1;
  const int l16 = lane & 15, g = lane >> 4;

  const int m0 = blockIdx.y * BM;
  const int n0 = blockIdx.x * BN;

  f32x4 acc[4][4] = {};
  const int o = tid * 16;

  for (int k0 = 0; k0 < GK; k0 += BK) {
#pragma unroll
    for (int i = 0; i < 4; ++i) {
      const int oo = o + i * 4096;
      const int row = oo >> 7, colb = oo & 127;
      gload_lds16(A + (size_t)(m0 + row) * (GK * 2) + (size_t)k0 * 2 + colb,
                  ((char*)&tA[0][0]) + i * 4096 + wid * 1024);
      gload_lds16(W + (size_t)(n0 + row) * (GK * 2) + (size_t)k0 * 2 + colb,
                  ((char*)&tW[0][0]) + i * 4096 + wid * 1024);
    }
    __syncthreads();
#pragma unroll
    for (int kk = 0; kk < 2; ++kk) {
      const int kcol = kk * 32 + g * 8;
      bf16x8 af[4], bfr[4];
#pragma unroll
      for (int m = 0; m < 4; ++m)
        af[m] = *(const bf16x8*)&tA[wm * 64 + m * 16 + l16][kcol];
#pragma unroll
      for (int n = 0; n < 4; ++n)
        bfr[n] = *(const bf16x8*)&tW[wn * 64 + n * 16 + l16][kcol];
#pragma unroll
      for (int m = 0; m < 4; ++m)
#pragma unroll
        for (int n = 0; n < 4; ++n)
          acc[m][n] = __builtin_amdgcn_mfma_f32_16x16x32_bf16(
              af[m], bfr[n], acc[m][n], 0, 0, 0);
    }
    __syncthreads();
  }

#pragma unroll
  for (int n = 0; n < 4; ++n) {
    const int col = n0 + wn * 64 + n * 16 + l16;
    const float bv = bias[col] * bsc;
#pragma unroll
    for (int m = 0; m < 4; ++m) {
      const int rbase = m0 + wm * 64 + m * 16 + g * 4;
#pragma unroll
      for (int r = 0; r < 4; ++r) {
        const float v = acc[m][n][r] + bv;
        if (CF32)
          ((float*)C)[(size_t)(rbase + r) * GN + col] = v;
        else
          ((uint16_t*)C)[(size_t)(rbase + r) * GN + col] = f2bf(v);
      }
    }
  }
}

// ---------------- V transpose: Vp[b*S+s][h*64+dk] -> Vt[(b*16+h)*64+dk][s] ---
__global__ __launch_bounds__(256) void transpose_v(
    const uint16_t* __restrict__ Vp, uint16_t* __restrict__ Vt) {
  __shared__ alignas(16) char T[64 * 128];
  const int tid = threadIdx.x;
  const int s0 = blockIdx.x * 64;
  const int h = blockIdx.y;
  const int bb = blockIdx.z;
#pragma unroll
  for (int it = 0; it < 2; ++it) {
    const int idx = tid + it * 256;
    const int row = idx >> 3;         // s within tile
    const int colb = (idx & 7) * 16;  // dk byte col
    const u32x4 v = *(const u32x4*)((const char*)Vp +
        (((size_t)bb * S_ + s0 + row) * D_ + h * DK_) * 2 + colb);
    *(u32x4*)(T + row * 128 + (colb ^ (((row >> 3) & 7) << 4))) = v;
  }
  __syncthreads();
#pragma unroll
  for (int it = 0; it < 2; ++it) {
    const int idx = tid + it * 256;
    const int dk = idx >> 3;
    const int sc = (idx & 7) * 8;
    union { uint16_t u[8]; u32x4 q; } o;
#pragma unroll
    for (int j = 0; j < 8; ++j) {
      const int row = sc + j;
      o.u[j] =
          *(const uint16_t*)(T + row * 128 + ((dk * 2) ^ (((row >> 3) & 7) << 4)));
    }
    *(u32x4*)((char*)Vt +
              (((size_t)(bb * H_ + h) * DK_ + dk) * S_ + s0 + sc) * 2) = o.q;
  }
}

// ---------------- flash attention v5 -----------------------------------------
// Swapped-operand QK^T (lane holds S^T column), reg-P via cvt_pk + shfl,
// KVBLK=128 dbuf + 1 barrier/tile, XCD-aware head-contiguous decode (T1),
// K/V^T staged via global_load_lds with pre-swizzled source (T2/T21).
__global__ __launch_bounds__(256) void mha_attn(
    const uint16_t* __restrict__ Q, const uint16_t* __restrict__ K,
    const uint16_t* __restrict__ Vt, uint16_t* __restrict__ O) {
  __shared__ alignas(16) char K_s[2][16384]; // [128 kv][128B]
  __shared__ alignas(16) char V_s[2][16384]; // [64 dk][256B kv]

  const int tid = threadIdx.x;
  const int lane = tid & 63;
  const int wid = tid >> 6;
  const int l16 = lane & 15, g = lane >> 4;

  // XCD-aware decode: d = xcd + 8*(h8*16 + qb); bh = xcd + 8*h8.
  const int d = blockIdx.x;
  const int bh = (d & 7) + ((d >> 7) << 3);
  const int qb = (d >> 3) & 15;
  const int b = bh >> 4, h = bh & 15;
  const int q0 = qb * QBLK;

  bf16x8 qf[2][2];
#pragma unroll
  for (int mi = 0; mi < 2; ++mi) {
    const uint16_t* qp = Q + ((size_t)(b * S_) + q0 + mi * 64 + wid * 16 + l16) * D_ +
                         h * DK_ + g * 8;
    qf[mi][0] = *(const bf16x8*)qp;
    qf[mi][1] = *(const bf16x8*)(qp + 32);
  }

  f32x4 o_acc[2][4] = {}; // o^T[dk=n*16+g*4+r][q=l16]
  float lpart[2] = {0.f, 0.f};

  const char* Kb = (const char*)K;
  const char* Vtb = (const char*)Vt;

  int srowK[4], scolK[4], srowV[4], scolV[4];
#pragma unroll
  for (int i = 0; i < 4; ++i) {
    const int oo = tid * 16 + i * 4096;
    srowK[i] = oo >> 7;                               // kv row, 128B rows
    scolK[i] = (oo & 127) ^ ((srowK[i] & 7) << 4);    // pre-swizzled src col
    srowV[i] = oo >> 8;                               // dk row, 256B rows
    scolV[i] = (oo & 255) ^ ((srowV[i] & 7) << 4);
  }

#define ISSUE_LOADS(buf, kv0)                                                  \
  {                                                                            \
    _Pragma("unroll") for (int i = 0; i < 4; ++i) {                            \
      gload_lds16(Kb + (((size_t)b * S_ + (kv0) + srowK[i]) * D_ + h * DK_) * 2\
                      + scolK[i],                                              \
                  &K_s[buf][0] + i * 4096 + wid * 1024);                       \
      gload_lds16(Vtb + (((size_t)bh * DK_ + srowV[i]) * S_ + (kv0)) * 2       \
                      + scolV[i],                                              \
                  &V_s[buf][0] + i * 4096 + wid * 1024);                       \
    }                                                                          \
  }

  ISSUE_LOADS(0, 0);
  __syncthreads();
  int cur = 0;

  const int bsrc = l16 + ((g & 1) << 5); // shuffle source base lane
  const int gsel = g >> 1;

  for (int kv0 = 0; kv0 < S_; kv0 += KVBLK) {
    const bool last = (kv0 + KVBLK >= S_);
    if (!last) ISSUE_LOADS(cur ^ 1, kv0 + KVBLK);

    // ---- swapped QK^T: sacc[mi][n] = S^T[kv=n*16+g*4+r][q=l16] ----
    f32x4 sacc[2][8] = {};
#pragma unroll
    for (int ks = 0; ks < 2; ++ks) {
      const int kcolb = ks * 64 + g * 16;
#pragma unroll
      for (int n = 0; n < 8; ++n) {
        const int kvr = n * 16 + l16;
        const bf16x8 kf =
            *(const bf16x8*)(&K_s[cur][0] + kvr * 128 + (kcolb ^ ((kvr & 7) << 4)));
#pragma unroll
        for (int mi = 0; mi < 2; ++mi)
          sacc[mi][n] = __builtin_amdgcn_mfma_f32_16x16x32_bf16(
              kf, qf[mi][ks], sacc[mi][n], 0, 0, 0);
      }
    }

    // ---- exp2 + pack + cross-g redistribution (P stays in regs) ----
    uint32_t pb[2][4][4];
#pragma unroll
    for (int mi = 0; mi < 2; ++mi) {
      uint32_t pk0[8][2];
#pragma unroll
      for (int n = 0; n < 8; ++n) {
        float e0 = EXP2F(sacc[mi][n][0]);
        float e1 = EXP2F(sacc[mi][n][1]);
        float e2 = EXP2F(sacc[mi][n][2]);
        float e3 = EXP2F(sacc[mi][n][3]);
        lpart[mi] += (e0 + e1) + (e2 + e3);
        pk0[n][0] = cvtpk(e0, e1);
        pk0[n][1] = cvtpk(e2, e3);
      }
#pragma unroll
      for (int ks = 0; ks < 4; ++ks)
#pragma unroll
        for (int jp = 0; jp < 4; ++jp) {
          const int srcl = bsrc + ((jp >> 1) << 4);
          const uint32_t va = __shfl(pk0[2 * ks][jp & 1], srcl, 64);
          const uint32_t vb = __shfl(pk0[2 * ks + 1][jp & 1], srcl, 64);
          pb[mi][ks][jp] = gsel ? vb : va;
        }
    }

    // ---- PV: o^T = mfma(V^T, P^T) ----
#pragma unroll
    for (int ks = 0; ks < 4; ++ks) {
      const int kcolb = ks * 64 + g * 16;
      bf16x8 pf[2];
#pragma unroll
      for (int mi = 0; mi < 2; ++mi) {
        u32x4 t = {pb[mi][ks][0], pb[mi][ks][1], pb[mi][ks][2], pb[mi][ks][3]};
        pf[mi] = __builtin_bit_cast(bf16x8, t);
      }
#pragma unroll
      for (int n = 0; n < 4; ++n) {
        const int dkr = n * 16 + l16;
        const bf16x8 vf =
            *(const bf16x8*)(&V_s[cur][0] + dkr * 256 + (kcolb ^ ((dkr & 7) << 4)));
#pragma unroll
        for (int mi = 0; mi < 2; ++mi)
          o_acc[mi][n] = __builtin_amdgcn_mfma_f32_16x16x32_bf16(
              vf, pf[mi], o_acc[mi][n], 0, 0, 0);
      }
    }

    if (!last) __syncthreads();
    cur ^= 1;
  }

  // ---- l-reduce across the 4 g-groups; normalize; packed 8B stores ----
  float linv[2];
#pragma unroll
  for (int mi = 0; mi < 2; ++mi) {
    float s_ = lpart[mi];
    s_ += __shfl_xor(s_, 16, 64);
    s_ += __shfl_xor(s_, 32, 64);
    linv[mi] = 1.f / s_;
  }
#pragma unroll
  for (int mi = 0; mi < 2; ++mi) {
    const size_t row = (size_t)b * S_ + q0 + mi * 64 + wid * 16 + l16;
    uint16_t* op = O + row * D_ + h * DK_ + g * 4;
#pragma unroll
    for (int n = 0; n < 4; ++n) {
      u32x2 w;
      w[0] = cvtpk(o_acc[mi][n][0] * linv[mi], o_acc[mi][n][1] * linv[mi]);
      w[1] = cvtpk(o_acc[mi][n][2] * linv[mi], o_acc[mi][n][3] * linv[mi]);
      *(u32x2*)(op + n * 16) = w;
    }
  }
}

extern "C" void kernel_launch(void* const* d_in, const int* in_sizes, int n_in,
                              void* d_out, int out_size, void* d_ws,
                              size_t ws_size, hipStream_t stream) {
  (void)in_sizes; (void)n_in; (void)out_size; (void)ws_size;

  const float* query = (const float*)d_in[0];
  const float* key_ = (const float*)d_in[1];
  const float* value = (const float*)d_in[2];
  const float* Wq = (const float*)d_in[3];
  const float* bq = (const float*)d_in[4];
  const float* Wk = (const float*)d_in[5];
  const float* bk = (const float*)d_in[6];
  const float* Wv = (const float*)d_in[7];
  const float* bv = (const float*)d_in[8];
  const float* Wo = (const float*)d_in[9];
  const float* bo = (const float*)d_in[10];

  const size_t nact = (size_t)GM * GN;
  const size_t nw = (size_t)GN * GK;
  uint16_t* p = (uint16_t*)d_ws;
  uint16_t* qb = p; p += nact;
  uint16_t* kb = p; p += nact;
  uint16_t* vb = p; p += nact;
  uint16_t* wq = p; p += nw;
  uint16_t* wk = p; p += nw;
  uint16_t* wv = p; p += nw;
  uint16_t* wo = p; p += nw;
  uint16_t* Qp = p; p += nact;
  uint16_t* Kp = p; p += nact;
  uint16_t* Vp = p; p += nact;
  uint16_t* Cp = p; p += nact;
  uint16_t* Vt = qb; // reuse: qb dead after QKV GEMM

  // ---- 1) convert to bf16 (Wq pre-scaled by log2(e)/sqrt(dk)) ----
  CvtArgs ca;
  const float* srcs[7] = {query, key_, value, Wq, Wk, Wv, Wo};
  uint16_t* dsts[7] = {qb, kb, vb, wq, wk, wv, wo};
  const int cnts[7] = {(int)nact, (int)nact, (int)nact, (int)nw,
                       (int)nw,   (int)nw,   (int)nw};
  for (int i = 0; i < 7; ++i) {
    ca.src[i] = srcs[i]; ca.dst[i] = dsts[i]; ca.n[i] = cnts[i];
    ca.scale[i] = 1.0f;
  }
  ca.scale[3] = SCALE_LOG2E; // Wq
  cvt_f32_bf16<<<dim3(512, 1, 7), dim3(256), 0, stream>>>(ca);

  // ---- 2) QKV projections (Q branch bias also pre-scaled) ----
  Gemm3Args g1;
  g1.A[0] = qb; g1.A[1] = kb; g1.A[2] = vb;
  g1.W[0] = wq; g1.W[1] = wk; g1.W[2] = wv;
  g1.bias[0] = bq; g1.bias[1] = bk; g1.bias[2] = bv;
  g1.bscale[0] = SCALE_LOG2E; g1.bscale[1] = 1.0f; g1.bscale[2] = 1.0f;
  g1.C[0] = Qp; g1.C[1] = Kp; g1.C[2] = Vp;
  mha_gemm3<false>
      <<<dim3(GN / BN, GM / BM, 3), dim3(256), 0, stream>>>(g1);

  // ---- 3) V transpose (into dead qb buffer) ----
  transpose_v<<<dim3(S_ / 64, H_, B_), dim3(256), 0, stream>>>(Vp, Vt);

  // ---- 4) attention (1D grid, XCD-swizzled decode in-kernel) ----
  mha_attn<<<dim3((S_ / QBLK) * B_ * H_), dim3(256), 0, stream>>>(Qp, Kp, Vt, Cp);

  // ---- 5) output projection (f32 out to d_out) ----
  Gemm3Args g2;
  g2.A[0] = Cp; g2.W[0] = wo; g2.bias[0] = bo; g2.C[0] = d_out;
  g2.bscale[0] = 1.0f;
  g2.A[1] = g2.A[0]; g2.W[1] = g2.W[0]; g2.bias[1] = g2.bias[0]; g2.C[1] = g2.C[0];
  g2.bscale[1] = 1.0f;
  g2.A[2] = g2.A[0]; g2.W[2] = g2.W[0]; g2.bias[2] = g2.bias[0]; g2.C[2] = g2.C[0];
  g2.bscale[2] = 1.0f;
  mha_gemm3<true>
      <<<dim3(GN / BN, GM / BM, 1), dim3(256), 0, stream>>>(g2);
}